// Round 5
// baseline (522.362 us; speedup 1.0000x reference)
//
#include <hip/hip_runtime.h>

#define BB 512
#define TT 512
#define KK 9
#define VP1 30001   // V+1 rows in emb
#define BTK ((size_t)BB * TT * KK)

typedef __attribute__((ext_vector_type(8))) short short8;
typedef __attribute__((ext_vector_type(4))) float float4v;

__device__ __forceinline__ float sigm(float x) {
    return __builtin_amdgcn_rcpf(1.0f + __expf(-x));
}
__device__ __forceinline__ float tanh_(float x) {
    return 1.0f - 2.0f * __builtin_amdgcn_rcpf(__expf(2.0f * x) + 1.0f);
}

__device__ __forceinline__ unsigned short f2bf(float f) {
    unsigned int u = __float_as_uint(f);
    unsigned int r = u + 0x7fffu + ((u >> 16) & 1u);
    return (unsigned short)(r >> 16);
}
__device__ __forceinline__ float bflo2f(unsigned int d) { return __uint_as_float(d << 16); }
__device__ __forceinline__ float bfhi2f(unsigned int d) { return __uint_as_float(d & 0xffff0000u); }

// barrier that does NOT drain vmcnt (keeps global prefetch loads in flight).
// 0xC07F = vmcnt(63) expcnt(7) lgkmcnt(0): wait LDS ops only.
__device__ __forceinline__ void block_sync_lds() {
    __builtin_amdgcn_s_waitcnt(0xC07F);
    __builtin_amdgcn_s_barrier();
}

// ---------------------------------------------------------------------------
// embW[v][c] (bf16), c = dir*256 + u*4 + g  <-  emb[v,:] @ W_dir[:, g*64+u] + b.
// W staged swizzled-bf16 in LDS (coalesced loads); C repacked through LDS ->
// coalesced dwordx4 stores.
// ---------------------------------------------------------------------------
__global__ __launch_bounds__(256, 1)
void embw_kernel(const float* __restrict__ emb,
                 const float* __restrict__ Wf, const float* __restrict__ bfv,
                 const float* __restrict__ Wb, const float* __restrict__ bbv,
                 unsigned short* __restrict__ embw)
{
    const int v0 = blockIdx.x * 64;
    const int tid = threadIdx.x;
    const int w = tid >> 6, lane = tid & 63;
    const int l16 = lane & 15, quad = lane >> 4;

    __shared__ __align__(16) unsigned short sm[512 * 72];   // wlds[512][72] / clds[64][520]
    __shared__ float blds[512];
    unsigned short (*wlds)[72]  = (unsigned short(*)[72])sm;
    unsigned short (*clds)[520] = (unsigned short(*)[520])sm;

    // stage W -> LDS, swizzled: wlds[c][k] = bf16(W_dir[k][g*64+u]), c=dir*256+u*4+g
#pragma unroll
    for (int it = 0; it < 128; ++it) {
        int idx = it * 256 + tid;
        int dir = idx >> 14, rem = idx & 16383;
        int k = rem >> 8, scol = rem & 255;
        int u = scol & 63, g = scol >> 6;
        float val = (dir ? Wb : Wf)[k * 256 + scol];
        wlds[dir * 256 + u * 4 + g][k] = f2bf(val);
    }
    {
        int c = tid, c2 = tid + 256;
        int u = c & 63 ? 0 : 0; // (placeholder no-op)
        // c -> scol: dir = c>>8, rem = c&255, u = rem>>2, g = rem&3 ; scol = g*64+u
        int dir0 = c >> 8, rem0 = c & 255;
        blds[c] = (dir0 ? bbv : bfv)[(rem0 & 3) * 64 + (rem0 >> 2)];
        int dir1 = c2 >> 8, rem1 = c2 & 255;
        blds[c2] = (dir1 ? bbv : bfv)[(rem1 & 3) * 64 + (rem1 >> 2)];
    }

    // A fragments (emb rows, f32 -> bf16)
    short8 aFr[4][2];
#pragma unroll
    for (int mt = 0; mt < 4; ++mt) {
        int vrow = v0 + mt * 16 + l16;
        if (vrow >= VP1) vrow = VP1 - 1;
        const float* er = emb + (size_t)vrow * 64;
#pragma unroll
        for (int q = 0; q < 2; ++q) {
            const float* p = er + q * 32 + quad * 8;
            float4 x0 = *(const float4*)(p);
            float4 x1 = *(const float4*)(p + 4);
            short8 v;
            v[0] = (short)f2bf(x0.x); v[1] = (short)f2bf(x0.y);
            v[2] = (short)f2bf(x0.z); v[3] = (short)f2bf(x0.w);
            v[4] = (short)f2bf(x1.x); v[5] = (short)f2bf(x1.y);
            v[6] = (short)f2bf(x1.z); v[7] = (short)f2bf(x1.w);
            aFr[mt][q] = v;
        }
    }
    __syncthreads();

    // B fragments from LDS
    short8 bFr[8][2];
    float biasn[8];
#pragma unroll
    for (int n = 0; n < 8; ++n) {
        int c = w * 128 + n * 16 + l16;
        biasn[n] = blds[c];
#pragma unroll
        for (int q = 0; q < 2; ++q)
            bFr[n][q] = *(const short8*)&wlds[c][q * 32 + quad * 8];
    }

    float4v acc[4][8];
#pragma unroll
    for (int mt = 0; mt < 4; ++mt)
#pragma unroll
        for (int n = 0; n < 8; ++n) {
            acc[mt][n][0] = biasn[n]; acc[mt][n][1] = biasn[n];
            acc[mt][n][2] = biasn[n]; acc[mt][n][3] = biasn[n];
        }
#pragma unroll
    for (int mt = 0; mt < 4; ++mt)
#pragma unroll
        for (int n = 0; n < 8; ++n) {
            acc[mt][n] = __builtin_amdgcn_mfma_f32_16x16x32_bf16(aFr[mt][0], bFr[n][0], acc[mt][n], 0, 0, 0);
            acc[mt][n] = __builtin_amdgcn_mfma_f32_16x16x32_bf16(aFr[mt][1], bFr[n][1], acc[mt][n], 0, 0, 0);
        }

    __syncthreads();   // done with wlds; reuse as clds

    // C -> LDS repack
#pragma unroll
    for (int mt = 0; mt < 4; ++mt)
#pragma unroll
        for (int n = 0; n < 8; ++n) {
            int cc = w * 128 + n * 16 + l16;
#pragma unroll
            for (int r = 0; r < 4; ++r)
                clds[mt * 16 + quad * 4 + r][cc] = f2bf(acc[mt][n][r]);
        }
    __syncthreads();

    // coalesced stores: 64 rows x 1024 B
#pragma unroll
    for (int it = 0; it < 16; ++it) {
        int idx = it * 256 + tid;
        int row = idx >> 6, chunk = idx & 63;
        if (v0 + row < VP1) {
            uint4 val = *(const uint4*)&clds[row][chunk * 8];
            *(uint4*)(embw + (size_t)(v0 + row) * 512 + chunk * 8) = val;
        }
    }
}

// ---------------------------------------------------------------------------
// Recurrence: grid 256, block = 2 rows x 2 dirs = 4 chains. 4 waves, wave w
// owns units u = w*16+l16. Fwd chains -> LDS tile 0 rows {0,4} (quads 0,1);
// bwd chains -> tile 1 rows {8,12} (quads 2,3). Two independent MFMA->gate
// chains per wave overlap; gates computed once on a cndmask-merged vector.
// ---------------------------------------------------------------------------
__global__ __launch_bounds__(256, 1)
void rec_kernel(const int* __restrict__ tokens,
                const unsigned short* __restrict__ embw,
                const float* __restrict__ Uf, const float* __restrict__ Ub,
                const float* __restrict__ Wd,
                float* __restrict__ potf)   // potb = potf + BTK
{
    const int row0 = blockIdx.x * 2;
    const int tid = threadIdx.x;
    const int lane = tid & 63;
    const int w = tid >> 6;
    const int l16 = lane & 15, quad = lane >> 4;
    const int u = w * 16 + l16;
    const int dirL = quad >> 1;        // this lane's chain direction
    const int rowL = quad & 1;         // this lane's local row
    const bool isA = (quad < 2);

    const uint2* embw2 = (const uint2*)embw;
    float* potD = potf + (size_t)dirL * BTK;   // per-lane output base

    __shared__ int tokl[2][TT];                               // 4 KB
    __shared__ __align__(16) unsigned short hl[2][2][16][72]; // [buf][tile][row][u]

    for (int i = tid; i < 2 * 2 * 16 * 72; i += 256)
        ((unsigned short*)hl)[i] = 0;
    for (int i = tid; i < 2 * TT; i += 256) {
        int r = i >> 9, t = i & 511;
        tokl[r][t] = tokens[(row0 + r) * TT + t];
    }

    // U B-fragments, both dirs: bU[d][g][q][j] = U_d[k=q*32+quad*8+j][g*64+u]
    short8 bU[2][4][2];
#pragma unroll
    for (int d = 0; d < 2; ++d) {
        const float* Up = d ? Ub : Uf;
#pragma unroll
        for (int g = 0; g < 4; ++g)
#pragma unroll
            for (int q = 0; q < 2; ++q) {
                short8 v;
#pragma unroll
                for (int j = 0; j < 8; ++j) {
                    int k = q * 32 + quad * 8 + j;
                    v[j] = (short)f2bf(Up[k * 256 + g * 64 + u]);
                }
                bU[d][g][q] = v;
            }
    }
    // Wd B-fragments, both dirs
    short8 bW[2][2];
#pragma unroll
    for (int d = 0; d < 2; ++d)
#pragma unroll
        for (int q = 0; q < 2; ++q) {
            short8 v;
#pragma unroll
            for (int j = 0; j < 8; ++j) {
                int k = q * 32 + quad * 8 + j;
                v[j] = (l16 < KK) ? (short)f2bf(Wd[(d * 64 + k) * KK + l16]) : (short)0;
            }
            bW[d][q] = v;
        }

    __syncthreads();  // hl zeroed + tokens staged (one-time full drain)

    // per-lane rings for this lane's chain
    int tokA[4], tokB[4];
    uint2 zxp[4];
#pragma unroll
    for (int d = 0; d < 4; ++d) {
        int td = dirL ? (TT - 1 - d) : d;
        int td4 = dirL ? (TT - 1 - (d + 4)) : (d + 4);
        tokA[d] = tokl[rowL][td];
        tokB[d] = tokl[rowL][td4];
    }
#pragma unroll
    for (int d = 0; d < 4; ++d)
        zxp[d] = embw2[(size_t)tokA[d] * 128 + dirL * 64 + u];

    float c_st = 0.f, h_st = 0.f;

    // persistent accumulators: elems 1..3 stay 0 forever (garbage rows are 0)
    float4v accA[4], accB[4];
#pragma unroll
    for (int g = 0; g < 4; ++g) {
        accA[g][0] = 0.f; accA[g][1] = 0.f; accA[g][2] = 0.f; accA[g][3] = 0.f;
        accB[g][0] = 0.f; accB[g][1] = 0.f; accB[g][2] = 0.f; accB[g][3] = 0.f;
    }

    for (int sb = 0; sb < TT; sb += 4) {
#pragma unroll
        for (int ss = 0; ss < 4; ++ss) {
            const int s = sb + ss;
            int tcur = tokA[ss];
            uint2 zcur = zxp[ss];

            // publish h entering step s: tile dirL, row quad*4
            hl[s & 1][dirL][quad * 4][u] = f2bf(h_st);

            // zx prefetch for step s+4 (survives raw barrier)
            if (s + 4 < TT)
                zxp[ss] = embw2[(size_t)tokB[ss] * 128 + dirL * 64 + u];
            tokA[ss] = tokB[ss];

            block_sync_lds();

            const unsigned short* hrowA = &hl[s & 1][0][l16][0];
            const unsigned short* hrowB = &hl[s & 1][1][l16][0];
            short8 a0A = *(const short8*)(hrowA + quad * 8);
            short8 a1A = *(const short8*)(hrowA + 32 + quad * 8);
            short8 a0B = *(const short8*)(hrowB + quad * 8);
            short8 a1B = *(const short8*)(hrowB + 32 + quad * 8);

            // token ring refill for step s+8
            if (s + 8 < TT) {
                int t8 = dirL ? (TT - 1 - (s + 8)) : (s + 8);
                tokB[ss] = tokl[rowL][t8];
            }

            // inject zx into elem 0 of both groups (only own group's is used)
            accA[0][0] = bflo2f(zcur.x); accB[0][0] = accA[0][0];
            accA[1][0] = bfhi2f(zcur.x); accB[1][0] = accA[1][0];
            accA[2][0] = bflo2f(zcur.y); accB[2][0] = accA[2][0];
            accA[3][0] = bfhi2f(zcur.y); accB[3][0] = accA[3][0];

#pragma unroll
            for (int g = 0; g < 4; ++g) {
                accA[g] = __builtin_amdgcn_mfma_f32_16x16x32_bf16(a0A, bU[0][g][0], accA[g], 0, 0, 0);
                accB[g] = __builtin_amdgcn_mfma_f32_16x16x32_bf16(a0B, bU[1][g][0], accB[g], 0, 0, 0);
                accA[g] = __builtin_amdgcn_mfma_f32_16x16x32_bf16(a1A, bU[0][g][1], accA[g], 0, 0, 0);
                accB[g] = __builtin_amdgcn_mfma_f32_16x16x32_bf16(a1B, bU[1][g][1], accB[g], 0, 0, 0);
            }

            // potentials for previous step (rotated across waves, both groups)
            if (s > 0 && w == (s & 3)) {
                float4v pA = {0.f, 0.f, 0.f, 0.f}, pB = {0.f, 0.f, 0.f, 0.f};
                pA = __builtin_amdgcn_mfma_f32_16x16x32_bf16(a0A, bW[0][0], pA, 0, 0, 0);
                pB = __builtin_amdgcn_mfma_f32_16x16x32_bf16(a0B, bW[1][0], pB, 0, 0, 0);
                pA = __builtin_amdgcn_mfma_f32_16x16x32_bf16(a1A, bW[0][1], pA, 0, 0, 0);
                pB = __builtin_amdgcn_mfma_f32_16x16x32_bf16(a1B, bW[1][1], pB, 0, 0, 0);
                if (l16 < KK) {
                    float pv = isA ? pA[0] : pB[0];
                    int tp = isA ? (s - 1) : (TT - s);
                    potD[((size_t)(row0 + rowL) * TT + tp) * KK + l16] = pv;
                }
            }

            // shared gates on merged vector
            {
                float zi = isA ? accA[0][0] : accB[0][0];
                float zf = isA ? accA[1][0] : accB[1][0];
                float zg = isA ? accA[2][0] : accB[2][0];
                float zo = isA ? accA[3][0] : accB[3][0];
                float cn = sigm(zf) * c_st + sigm(zi) * tanh_(zg);
                float hn = sigm(zo) * tanh_(cn);
                bool m = (tcur != 0);
                h_st = m ? hn : h_st;
                c_st = m ? cn : c_st;
            }
        }
    }

    // epilogue: final step's potential (buffer parity TT&1 == 0)
    hl[0][dirL][quad * 4][u] = f2bf(h_st);
    block_sync_lds();
    if (w == 0) {
        const unsigned short* hrowA = &hl[0][0][l16][0];
        const unsigned short* hrowB = &hl[0][1][l16][0];
        short8 a0A = *(const short8*)(hrowA + quad * 8);
        short8 a1A = *(const short8*)(hrowA + 32 + quad * 8);
        short8 a0B = *(const short8*)(hrowB + quad * 8);
        short8 a1B = *(const short8*)(hrowB + 32 + quad * 8);
        float4v pA = {0.f, 0.f, 0.f, 0.f}, pB = {0.f, 0.f, 0.f, 0.f};
        pA = __builtin_amdgcn_mfma_f32_16x16x32_bf16(a0A, bW[0][0], pA, 0, 0, 0);
        pB = __builtin_amdgcn_mfma_f32_16x16x32_bf16(a0B, bW[1][0], pB, 0, 0, 0);
        pA = __builtin_amdgcn_mfma_f32_16x16x32_bf16(a1A, bW[0][1], pA, 0, 0, 0);
        pB = __builtin_amdgcn_mfma_f32_16x16x32_bf16(a1B, bW[1][1], pB, 0, 0, 0);
        if (l16 < KK) {
            float pv = isA ? pA[0] : pB[0];
            int tl = isA ? (TT - 1) : 0;
            potD[((size_t)(row0 + rowL) * TT + tl) * KK + l16] = pv;
        }
    }
}

// ---------------------------------------------------------------------------
// Fused combine + Viterbi (one wave per row; tree argmax; parallel backtrace)
// ---------------------------------------------------------------------------
__global__ __launch_bounds__(64)
void viterbi_kernel(const int* __restrict__ tokens,
                    const float* __restrict__ potf, const float* __restrict__ potb,
                    const float* __restrict__ bd, const float* __restrict__ trans,
                    float* __restrict__ dec_out, float* __restrict__ pot_out,
                    float* __restrict__ seq_out)
{
    const int row = blockIdx.x;
    const int lane = threadIdx.x;

    __shared__ float pl[TT * KK];
    __shared__ unsigned char bpl[(TT - 1) * KK];
    __shared__ unsigned char maskl[TT];
    __shared__ unsigned char segmap[64][KK];
    __shared__ unsigned char bseq[65];
    __shared__ float decl_[TT];

    int cnt = 0;
#pragma unroll
    for (int ch = 0; ch < TT / 64; ++ch) {
        int tk = tokens[row * TT + ch * 64 + lane];
        int m = (tk != 0) ? 1 : 0;
        maskl[ch * 64 + lane] = (unsigned char)m;
        cnt += m;
    }
    for (int off = 32; off > 0; off >>= 1) cnt += __shfl_down(cnt, off);
    if (lane == 0) seq_out[row] = (float)cnt;

    const size_t base = (size_t)row * (TT * KK);
    for (int i = 0; i < (TT * KK) / 64; ++i) {
        int li = i * 64 + lane;
        float s = potf[base + li] + potb[base + li];
        pl[li] = s;
        pot_out[base + li] = s + bd[li % KK];
    }
    __syncthreads();

    float bdv = (lane < KK) ? bd[lane] : 0.f;
    float treg[KK];
#pragma unroll
    for (int i = 0; i < KK; ++i) treg[i] = (lane < KK) ? trans[i * KK + lane] : 0.f;

    float alpha = (lane < KK) ? (pl[lane] + bdv) : -1e30f;
    for (int t = 1; t < TT; ++t) {
        float p = (lane < KK) ? (pl[t * KK + lane] + bdv) : 0.f;
        float sc[KK];
#pragma unroll
        for (int i = 0; i < KK; ++i) sc[i] = __shfl(alpha, i) + treg[i];
        float b0 = sc[0]; int i0 = 0;
        if (sc[1] > b0) { b0 = sc[1]; i0 = 1; }
        float b1 = sc[2]; int i1 = 2;
        if (sc[3] > b1) { b1 = sc[3]; i1 = 3; }
        float b2 = sc[4]; int i2 = 4;
        if (sc[5] > b2) { b2 = sc[5]; i2 = 5; }
        float b3 = sc[6]; int i3 = 6;
        if (sc[7] > b3) { b3 = sc[7]; i3 = 7; }
        if (b1 > b0) { b0 = b1; i0 = i1; }
        if (b3 > b2) { b2 = b3; i2 = i3; }
        if (b2 > b0) { b0 = b2; i0 = i2; }
        if (sc[8] > b0) { b0 = sc[8]; i0 = 8; }

        bool m = maskl[t] != 0;
        alpha = m ? (b0 + p) : alpha;
        int bpv = m ? i0 : lane;
        if (lane < KK) bpl[(t - 1) * KK + lane] = (unsigned char)bpv;
    }
    float sc[KK];
#pragma unroll
    for (int i = 0; i < KK; ++i) sc[i] = __shfl(alpha, i);
    float b0 = sc[0]; int last = 0;
#pragma unroll
    for (int i = 1; i < KK; ++i)
        if (sc[i] > b0) { b0 = sc[i]; last = i; }
    __syncthreads();

    {
        int l = lane;
#pragma unroll
        for (int x = 0; x < KK; ++x) {
            int y = x;
#pragma unroll
            for (int d = 7; d >= 0; --d) {
                int t = 8 * l + d;
                if (t < TT - 1) y = bpl[t * KK + y];
            }
            segmap[l][x] = (unsigned char)y;
        }
    }
    __syncthreads();
    if (lane == 0) {
        int cur = last;
        bseq[64] = (unsigned char)last;
        for (int l = 63; l >= 0; --l) {
            cur = segmap[l][cur];
            bseq[l] = (unsigned char)cur;
        }
    }
    __syncthreads();
    {
        int l = lane;
        int cur = bseq[l + 1];
#pragma unroll
        for (int d = 7; d >= 0; --d) {
            int t = 8 * l + d;
            if (t < TT - 1) cur = bpl[t * KK + cur];
            decl_[t] = (maskl[t] != 0) ? (float)cur : 0.f;
        }
    }
    __syncthreads();
#pragma unroll
    for (int ch = 0; ch < TT / 64; ++ch)
        dec_out[(size_t)row * TT + ch * 64 + lane] = decl_[ch * 64 + lane];
}

extern "C" void kernel_launch(void* const* d_in, const int* in_sizes, int n_in,
                              void* d_out, int out_size, void* d_ws, size_t ws_size,
                              hipStream_t stream)
{
    const int*   tokens = (const int*)d_in[0];
    const float* emb    = (const float*)d_in[1];
    const float* Wf     = (const float*)d_in[2];
    const float* Uf     = (const float*)d_in[3];
    const float* bfv    = (const float*)d_in[4];
    const float* Wb     = (const float*)d_in[5];
    const float* Ub     = (const float*)d_in[6];
    const float* bbv    = (const float*)d_in[7];
    const float* Wd     = (const float*)d_in[8];
    const float* bd     = (const float*)d_in[9];
    const float* trans  = (const float*)d_in[10];

    float* out     = (float*)d_out;
    float* dec_out = out;
    float* pot_out = out + (size_t)BB * TT;
    float* seq_out = out + (size_t)BB * TT + BTK;

    float* potf = (float*)d_ws;
    float* potb = potf + BTK;
    unsigned short* embw = (unsigned short*)(potb + BTK);

    hipLaunchKernelGGL(embw_kernel, dim3(469), dim3(256), 0, stream,
                       emb, Wf, bfv, Wb, bbv, embw);
    hipLaunchKernelGGL(rec_kernel, dim3(256), dim3(256), 0, stream,
                       tokens, embw, Uf, Ub, Wd, potf);
    hipLaunchKernelGGL(viterbi_kernel, dim3(BB), dim3(64), 0, stream,
                       tokens, potf, potb, bd, trans, dec_out, pot_out, seq_out);
}

// Round 6
// 431.434 us; speedup vs baseline: 1.2108x; 1.2108x over previous
//
#include <hip/hip_runtime.h>

#define BB 512
#define TT 512
#define KK 9
#define VP1 30001   // V+1 rows in emb
#define BTK ((size_t)BB * TT * KK)

typedef __attribute__((ext_vector_type(8))) short short8;
typedef __attribute__((ext_vector_type(4))) float float4v;

__device__ __forceinline__ float sigm(float x) {
    return __builtin_amdgcn_rcpf(1.0f + __expf(-x));
}
__device__ __forceinline__ float tanh_(float x) {
    return 1.0f - 2.0f * __builtin_amdgcn_rcpf(__expf(2.0f * x) + 1.0f);
}

__device__ __forceinline__ unsigned short f2bf(float f) {
    unsigned int u = __float_as_uint(f);
    unsigned int r = u + 0x7fffu + ((u >> 16) & 1u);
    return (unsigned short)(r >> 16);
}
__device__ __forceinline__ float bflo2f(unsigned int d) { return __uint_as_float(d << 16); }
__device__ __forceinline__ float bfhi2f(unsigned int d) { return __uint_as_float(d & 0xffff0000u); }

// barrier that does NOT drain vmcnt (keeps global prefetch loads in flight).
// 0xC07F = vmcnt(63) expcnt(7) lgkmcnt(0): wait LDS ops only.
__device__ __forceinline__ void block_sync_lds() {
    __builtin_amdgcn_s_waitcnt(0xC07F);
    __builtin_amdgcn_s_barrier();
}

// ---------------------------------------------------------------------------
// embW[v][c] (bf16), c = dir*256 + u*4 + g  <-  emb[v,:] @ W_dir[:, g*64+u] + b.
// W staged swizzled-bf16 in LDS; C repacked through LDS -> coalesced stores.
// ---------------------------------------------------------------------------
__global__ __launch_bounds__(256, 1)
void embw_kernel(const float* __restrict__ emb,
                 const float* __restrict__ Wf, const float* __restrict__ bfv,
                 const float* __restrict__ Wb, const float* __restrict__ bbv,
                 unsigned short* __restrict__ embw)
{
    const int v0 = blockIdx.x * 64;
    const int tid = threadIdx.x;
    const int w = tid >> 6, lane = tid & 63;
    const int l16 = lane & 15, quad = lane >> 4;

    __shared__ __align__(16) unsigned short sm[512 * 72];   // wlds[512][72] / clds[64][520]
    __shared__ float blds[512];
    unsigned short (*wlds)[72]  = (unsigned short(*)[72])sm;
    unsigned short (*clds)[520] = (unsigned short(*)[520])sm;

    // stage W -> LDS, swizzled: wlds[c][k] = bf16(W_dir[k][g*64+u]), c=dir*256+u*4+g
#pragma unroll
    for (int it = 0; it < 128; ++it) {
        int idx = it * 256 + tid;
        int dir = idx >> 14, rem = idx & 16383;
        int k = rem >> 8, scol = rem & 255;
        int u = scol & 63, g = scol >> 6;
        float val = (dir ? Wb : Wf)[k * 256 + scol];
        wlds[dir * 256 + u * 4 + g][k] = f2bf(val);
    }
    {
        int c = tid, c2 = tid + 256;
        int dir0 = c >> 8, rem0 = c & 255;
        blds[c] = (dir0 ? bbv : bfv)[(rem0 & 3) * 64 + (rem0 >> 2)];
        int dir1 = c2 >> 8, rem1 = c2 & 255;
        blds[c2] = (dir1 ? bbv : bfv)[(rem1 & 3) * 64 + (rem1 >> 2)];
    }

    // A fragments (emb rows, f32 -> bf16)
    short8 aFr[4][2];
#pragma unroll
    for (int mt = 0; mt < 4; ++mt) {
        int vrow = v0 + mt * 16 + l16;
        if (vrow >= VP1) vrow = VP1 - 1;
        const float* er = emb + (size_t)vrow * 64;
#pragma unroll
        for (int q = 0; q < 2; ++q) {
            const float* p = er + q * 32 + quad * 8;
            float4 x0 = *(const float4*)(p);
            float4 x1 = *(const float4*)(p + 4);
            short8 v;
            v[0] = (short)f2bf(x0.x); v[1] = (short)f2bf(x0.y);
            v[2] = (short)f2bf(x0.z); v[3] = (short)f2bf(x0.w);
            v[4] = (short)f2bf(x1.x); v[5] = (short)f2bf(x1.y);
            v[6] = (short)f2bf(x1.z); v[7] = (short)f2bf(x1.w);
            aFr[mt][q] = v;
        }
    }
    __syncthreads();

    // B fragments from LDS
    short8 bFr[8][2];
    float biasn[8];
#pragma unroll
    for (int n = 0; n < 8; ++n) {
        int c = w * 128 + n * 16 + l16;
        biasn[n] = blds[c];
#pragma unroll
        for (int q = 0; q < 2; ++q)
            bFr[n][q] = *(const short8*)&wlds[c][q * 32 + quad * 8];
    }

    float4v acc[4][8];
#pragma unroll
    for (int mt = 0; mt < 4; ++mt)
#pragma unroll
        for (int n = 0; n < 8; ++n) {
            acc[mt][n][0] = biasn[n]; acc[mt][n][1] = biasn[n];
            acc[mt][n][2] = biasn[n]; acc[mt][n][3] = biasn[n];
        }
#pragma unroll
    for (int mt = 0; mt < 4; ++mt)
#pragma unroll
        for (int n = 0; n < 8; ++n) {
            acc[mt][n] = __builtin_amdgcn_mfma_f32_16x16x32_bf16(aFr[mt][0], bFr[n][0], acc[mt][n], 0, 0, 0);
            acc[mt][n] = __builtin_amdgcn_mfma_f32_16x16x32_bf16(aFr[mt][1], bFr[n][1], acc[mt][n], 0, 0, 0);
        }

    __syncthreads();   // done with wlds; reuse as clds

#pragma unroll
    for (int mt = 0; mt < 4; ++mt)
#pragma unroll
        for (int n = 0; n < 8; ++n) {
            int cc = w * 128 + n * 16 + l16;
#pragma unroll
            for (int r = 0; r < 4; ++r)
                clds[mt * 16 + quad * 4 + r][cc] = f2bf(acc[mt][n][r]);
        }
    __syncthreads();

#pragma unroll
    for (int it = 0; it < 16; ++it) {
        int idx = it * 256 + tid;
        int row = idx >> 6, chunk = idx & 63;
        if (v0 + row < VP1) {
            uint4 val = *(const uint4*)&clds[row][chunk * 8];
            *(uint4*)(embw + (size_t)(v0 + row) * 512 + chunk * 8) = val;
        }
    }
}

// ---------------------------------------------------------------------------
// Recurrence: grid 256 = 2 dirs x 128 slices of 4 rows (R4 structure).
// Real rows at MFMA C rows {0,4,8,12} (reg 0); garbage rows zero in LDS, so
// accumulator elems 1..3 stay 0 forever -> persistent acc, no re-zeroing.
// 32-bit incremental pot offsets; hoisted embw gather base.
// ---------------------------------------------------------------------------
__global__ __launch_bounds__(256, 1)
void rec_kernel(const int* __restrict__ tokens,
                const unsigned short* __restrict__ embw,
                const float* __restrict__ Uf, const float* __restrict__ Ub,
                const float* __restrict__ Wd,
                float* __restrict__ potf, float* __restrict__ potb)
{
    const int blk = blockIdx.x;
    const int dir = blk >> 7;
    const int row0 = (blk & 127) * 4;
    const int tid = threadIdx.x;
    const int lane = tid & 63;
    const int w = tid >> 6;
    const int l16 = lane & 15, quad = lane >> 4;
    const int u = w * 16 + l16;

    const float* Up = dir ? Ub : Uf;
    float* pot = dir ? potb : potf;
    const uint2* ebase = (const uint2*)embw + dir * 64 + u;   // hoisted gather base

    __shared__ int tokl[4][TT];                        // 8 KB
    __shared__ __align__(16) unsigned short hl[2][16][72];

    for (int i = tid; i < 2 * 16 * 72; i += 256)
        ((unsigned short*)hl)[i] = 0;
    for (int i = tid; i < 4 * TT; i += 256) {
        int r = i >> 9, t = i & 511;
        tokl[r][t] = tokens[(row0 + r) * TT + t];
    }

    // U B-fragments: bU[g][q][j] = U[k=q*32+quad*8+j][g*64+u]
    short8 bU[4][2];
#pragma unroll
    for (int g = 0; g < 4; ++g)
#pragma unroll
        for (int q = 0; q < 2; ++q) {
            short8 v;
#pragma unroll
            for (int j = 0; j < 8; ++j) {
                int k = q * 32 + quad * 8 + j;
                v[j] = (short)f2bf(Up[k * 256 + g * 64 + u]);
            }
            bU[g][q] = v;
        }
    // Wd B-fragments
    short8 bW[2];
#pragma unroll
    for (int q = 0; q < 2; ++q) {
        short8 v;
#pragma unroll
        for (int j = 0; j < 8; ++j) {
            int k = q * 32 + quad * 8 + j;
            v[j] = (l16 < KK) ? (short)f2bf(Wd[(dir * 64 + k) * KK + l16]) : (short)0;
        }
        bW[q] = v;
    }

    __syncthreads();  // hl zeroed + tokens staged (one-time full drain)

    // rings: tokA = steps s..s+3, tokB = s+4..s+7 (row_local = quad)
    int tokA[4], tokB[4];
    uint2 zxp[4];
#pragma unroll
    for (int d = 0; d < 4; ++d) {
        int td = dir ? (TT - 1 - d) : d;
        int td4 = dir ? (TT - 1 - (d + 4)) : (d + 4);
        tokA[d] = tokl[quad][td];
        tokB[d] = tokl[quad][td4];
    }
#pragma unroll
    for (int d = 0; d < 4; ++d)
        zxp[d] = ebase[(size_t)tokA[d] << 7];

    float c_st = 0.f, h_st = 0.f;

    // persistent accumulators: elems 1..3 stay 0 forever (garbage rows are 0)
    float4v accg[4];
#pragma unroll
    for (int g = 0; g < 4; ++g) {
        accg[g][0] = 0.f; accg[g][1] = 0.f; accg[g][2] = 0.f; accg[g][3] = 0.f;
    }

    // incremental pot offset (bytes): this wave stores at s = w, w+4, ... (s>0);
    // tprev = s-1 (fwd) or TT-s (bwd); first tprev = w-1 / 3 (fwd), TT-w / TT-4 (bwd)
    const int tprev0 = dir ? (w == 0 ? TT - 4 : TT - w) : (w == 0 ? 3 : w - 1);
    int vOff = (((row0 + quad) * TT + tprev0) * KK + l16) * 4;
    const int vStep = (dir ? -4 : 4) * KK * 4;

    for (int sb = 0; sb < TT; sb += 4) {
#pragma unroll
        for (int ss = 0; ss < 4; ++ss) {
            const int s = sb + ss;
            int tcur = tokA[ss];
            uint2 zcur = zxp[ss];

            // publish h (state entering step s) -> row quad*4 (s&1 == ss&1, static)
            hl[ss & 1][quad * 4][u] = f2bf(h_st);

            // zx prefetch for step s+4 (survives raw barrier)
            if (s + 4 < TT)
                zxp[ss] = ebase[(size_t)tokB[ss] << 7];
            tokA[ss] = tokB[ss];

            block_sync_lds();

            const unsigned short* hrow = &hl[ss & 1][l16][0];
            short8 a0 = *(const short8*)(hrow + quad * 8);
            short8 a1 = *(const short8*)(hrow + 32 + quad * 8);

            // token ring refill for step s+8
            if (s + 8 < TT) {
                int t8 = dir ? (TT - 1 - (s + 8)) : (s + 8);
                tokB[ss] = tokl[quad][t8];
            }

            // z = zx + h @ U  (elem 0 only is real; 1..3 persist as 0)
            accg[0][0] = bflo2f(zcur.x);
            accg[1][0] = bfhi2f(zcur.x);
            accg[2][0] = bflo2f(zcur.y);
            accg[3][0] = bfhi2f(zcur.y);
#pragma unroll
            for (int g = 0; g < 4; ++g) {
                accg[g] = __builtin_amdgcn_mfma_f32_16x16x32_bf16(a0, bU[g][0], accg[g], 0, 0, 0);
                accg[g] = __builtin_amdgcn_mfma_f32_16x16x32_bf16(a1, bU[g][1], accg[g], 0, 0, 0);
            }

            // potentials for previous step: wave w handles s with (s&3)==w
            if (w == ss && s > 0) {
                float4v accP = {0.f, 0.f, 0.f, 0.f};
                accP = __builtin_amdgcn_mfma_f32_16x16x32_bf16(a0, bW[0], accP, 0, 0, 0);
                accP = __builtin_amdgcn_mfma_f32_16x16x32_bf16(a1, bW[1], accP, 0, 0, 0);
                if (l16 < KK)
                    *(float*)((char*)pot + vOff) = accP[0];
                vOff += vStep;
            }

            // gates: ONE element per lane
            {
                float zi = accg[0][0], zf = accg[1][0], zg = accg[2][0], zo = accg[3][0];
                float cn = sigm(zf) * c_st + sigm(zi) * tanh_(zg);
                float hn = sigm(zo) * tanh_(cn);
                bool m = (tcur != 0);
                h_st = m ? hn : h_st;
                c_st = m ? cn : c_st;
            }
        }
    }

    // epilogue: final step's potential (buffer parity TT&1 == 0)
    hl[0][quad * 4][u] = f2bf(h_st);
    block_sync_lds();
    if (w == 0) {
        const unsigned short* hrow = &hl[0][l16][0];
        short8 a0 = *(const short8*)(hrow + quad * 8);
        short8 a1 = *(const short8*)(hrow + 32 + quad * 8);
        float4v accP = {0.f, 0.f, 0.f, 0.f};
        accP = __builtin_amdgcn_mfma_f32_16x16x32_bf16(a0, bW[0], accP, 0, 0, 0);
        accP = __builtin_amdgcn_mfma_f32_16x16x32_bf16(a1, bW[1], accP, 0, 0, 0);
        int tlast = dir ? 0 : (TT - 1);
        if (l16 < KK)
            pot[((size_t)(row0 + quad) * TT + tlast) * KK + l16] = accP[0];
    }
}

// ---------------------------------------------------------------------------
// Fused combine + Viterbi (one wave per row; tree argmax; p/mask prefetch;
// parallel backtrace)
// ---------------------------------------------------------------------------
__global__ __launch_bounds__(64)
void viterbi_kernel(const int* __restrict__ tokens,
                    const float* __restrict__ potf, const float* __restrict__ potb,
                    const float* __restrict__ bd, const float* __restrict__ trans,
                    float* __restrict__ dec_out, float* __restrict__ pot_out,
                    float* __restrict__ seq_out)
{
    const int row = blockIdx.x;
    const int lane = threadIdx.x;

    __shared__ float pl[TT * KK];
    __shared__ unsigned char bpl[(TT - 1) * KK];
    __shared__ unsigned char maskl[TT];
    __shared__ unsigned char segmap[64][KK];
    __shared__ unsigned char bseq[65];
    __shared__ float decl_[TT];

    int cnt = 0;
#pragma unroll
    for (int ch = 0; ch < TT / 64; ++ch) {
        int tk = tokens[row * TT + ch * 64 + lane];
        int m = (tk != 0) ? 1 : 0;
        maskl[ch * 64 + lane] = (unsigned char)m;
        cnt += m;
    }
    for (int off = 32; off > 0; off >>= 1) cnt += __shfl_down(cnt, off);
    if (lane == 0) seq_out[row] = (float)cnt;

    const size_t base = (size_t)row * (TT * KK);
    for (int i = 0; i < (TT * KK) / 64; ++i) {
        int li = i * 64 + lane;
        float s = potf[base + li] + potb[base + li];
        pl[li] = s;
        pot_out[base + li] = s + bd[li % KK];
    }
    __syncthreads();

    float bdv = (lane < KK) ? bd[lane] : 0.f;
    float treg[KK];
#pragma unroll
    for (int i = 0; i < KK; ++i) treg[i] = (lane < KK) ? trans[i * KK + lane] : 0.f;

    float alpha = (lane < KK) ? (pl[lane] + bdv) : -1e30f;
    float pnext = (lane < KK) ? pl[KK + lane] : 0.f;
    int mnext = maskl[1];
    for (int t = 1; t < TT; ++t) {
        float p = pnext + bdv;
        int m = mnext;
        if (t + 1 < TT) {
            pnext = (lane < KK) ? pl[(t + 1) * KK + lane] : 0.f;
            mnext = maskl[t + 1];
        }
        float sc[KK];
#pragma unroll
        for (int i = 0; i < KK; ++i) sc[i] = __shfl(alpha, i) + treg[i];
        float b0 = sc[0]; int i0 = 0;
        if (sc[1] > b0) { b0 = sc[1]; i0 = 1; }
        float b1 = sc[2]; int i1 = 2;
        if (sc[3] > b1) { b1 = sc[3]; i1 = 3; }
        float b2 = sc[4]; int i2 = 4;
        if (sc[5] > b2) { b2 = sc[5]; i2 = 5; }
        float b3 = sc[6]; int i3 = 6;
        if (sc[7] > b3) { b3 = sc[7]; i3 = 7; }
        if (b1 > b0) { b0 = b1; i0 = i1; }
        if (b3 > b2) { b2 = b3; i2 = i3; }
        if (b2 > b0) { b0 = b2; i0 = i2; }
        if (sc[8] > b0) { b0 = sc[8]; i0 = 8; }

        alpha = m ? (b0 + p) : alpha;
        int bpv = m ? i0 : lane;
        if (lane < KK) bpl[(t - 1) * KK + lane] = (unsigned char)bpv;
    }
    float sc[KK];
#pragma unroll
    for (int i = 0; i < KK; ++i) sc[i] = __shfl(alpha, i);
    float b0 = sc[0]; int last = 0;
#pragma unroll
    for (int i = 1; i < KK; ++i)
        if (sc[i] > b0) { b0 = sc[i]; last = i; }
    __syncthreads();

    {
        int l = lane;
#pragma unroll
        for (int x = 0; x < KK; ++x) {
            int y = x;
#pragma unroll
            for (int d = 7; d >= 0; --d) {
                int t = 8 * l + d;
                if (t < TT - 1) y = bpl[t * KK + y];
            }
            segmap[l][x] = (unsigned char)y;
        }
    }
    __syncthreads();
    if (lane == 0) {
        int cur = last;
        bseq[64] = (unsigned char)last;
        for (int l = 63; l >= 0; --l) {
            cur = segmap[l][cur];
            bseq[l] = (unsigned char)cur;
        }
    }
    __syncthreads();
    {
        int l = lane;
        int cur = bseq[l + 1];
#pragma unroll
        for (int d = 7; d >= 0; --d) {
            int t = 8 * l + d;
            if (t < TT - 1) cur = bpl[t * KK + cur];
            decl_[t] = (maskl[t] != 0) ? (float)cur : 0.f;
        }
    }
    __syncthreads();
#pragma unroll
    for (int ch = 0; ch < TT / 64; ++ch)
        dec_out[(size_t)row * TT + ch * 64 + lane] = decl_[ch * 64 + lane];
}

extern "C" void kernel_launch(void* const* d_in, const int* in_sizes, int n_in,
                              void* d_out, int out_size, void* d_ws, size_t ws_size,
                              hipStream_t stream)
{
    const int*   tokens = (const int*)d_in[0];
    const float* emb    = (const float*)d_in[1];
    const float* Wf     = (const float*)d_in[2];
    const float* Uf     = (const float*)d_in[3];
    const float* bfv    = (const float*)d_in[4];
    const float* Wb     = (const float*)d_in[5];
    const float* Ub     = (const float*)d_in[6];
    const float* bbv    = (const float*)d_in[7];
    const float* Wd     = (const float*)d_in[8];
    const float* bd     = (const float*)d_in[9];
    const float* trans  = (const float*)d_in[10];

    float* out     = (float*)d_out;
    float* dec_out = out;
    float* pot_out = out + (size_t)BB * TT;
    float* seq_out = out + (size_t)BB * TT + BTK;

    float* potf = (float*)d_ws;
    float* potb = potf + BTK;
    unsigned short* embw = (unsigned short*)(potb + BTK);

    hipLaunchKernelGGL(embw_kernel, dim3(469), dim3(256), 0, stream,
                       emb, Wf, bfv, Wb, bbv, embw);
    hipLaunchKernelGGL(rec_kernel, dim3(256), dim3(256), 0, stream,
                       tokens, embw, Uf, Ub, Wd, potf, potb);
    hipLaunchKernelGGL(viterbi_kernel, dim3(BB), dim3(64), 0, stream,
                       tokens, potf, potb, bd, trans, dec_out, pot_out, seq_out);
}

// Round 7
// 399.413 us; speedup vs baseline: 1.3078x; 1.0802x over previous
//
#include <hip/hip_runtime.h>

#define BB 512
#define TT 512
#define KK 9
#define VP1 30001   // V+1 rows in emb
#define BTK ((size_t)BB * TT * KK)

typedef __attribute__((ext_vector_type(8))) short short8;
typedef __attribute__((ext_vector_type(4))) float float4v;

__device__ __forceinline__ float sigm(float x) {
    return __builtin_amdgcn_rcpf(1.0f + __expf(-x));
}
__device__ __forceinline__ float tanh_(float x) {
    return 1.0f - 2.0f * __builtin_amdgcn_rcpf(__expf(2.0f * x) + 1.0f);
}

__device__ __forceinline__ unsigned short f2bf(float f) {
    unsigned int u = __float_as_uint(f);
    unsigned int r = u + 0x7fffu + ((u >> 16) & 1u);
    return (unsigned short)(r >> 16);
}
__device__ __forceinline__ float bflo2f(unsigned int d) { return __uint_as_float(d << 16); }
__device__ __forceinline__ float bfhi2f(unsigned int d) { return __uint_as_float(d & 0xffff0000u); }

// broadcast lane i's float via SGPR (no LDS latency, unlike __shfl/ds_bpermute)
__device__ __forceinline__ float bcast(float v, int i) {
    return __uint_as_float(__builtin_amdgcn_readlane(__float_as_uint(v), i));
}

// barrier that does NOT drain vmcnt (keeps global prefetch loads in flight).
// 0xC07F = vmcnt(63) expcnt(7) lgkmcnt(0): wait LDS ops only.
__device__ __forceinline__ void block_sync_lds() {
    __builtin_amdgcn_s_waitcnt(0xC07F);
    __builtin_amdgcn_s_barrier();
}

// ---------------------------------------------------------------------------
// embW[v][c] (bf16), c = dir*256 + u*4 + g  <-  emb[v,:] @ W_dir[:, g*64+u] + b.
// (unchanged from R6)
// ---------------------------------------------------------------------------
__global__ __launch_bounds__(256, 1)
void embw_kernel(const float* __restrict__ emb,
                 const float* __restrict__ Wf, const float* __restrict__ bfv,
                 const float* __restrict__ Wb, const float* __restrict__ bbv,
                 unsigned short* __restrict__ embw)
{
    const int v0 = blockIdx.x * 64;
    const int tid = threadIdx.x;
    const int w = tid >> 6, lane = tid & 63;
    const int l16 = lane & 15, quad = lane >> 4;

    __shared__ __align__(16) unsigned short sm[512 * 72];   // wlds[512][72] / clds[64][520]
    __shared__ float blds[512];
    unsigned short (*wlds)[72]  = (unsigned short(*)[72])sm;
    unsigned short (*clds)[520] = (unsigned short(*)[520])sm;

#pragma unroll
    for (int it = 0; it < 128; ++it) {
        int idx = it * 256 + tid;
        int dir = idx >> 14, rem = idx & 16383;
        int k = rem >> 8, scol = rem & 255;
        int u = scol & 63, g = scol >> 6;
        float val = (dir ? Wb : Wf)[k * 256 + scol];
        wlds[dir * 256 + u * 4 + g][k] = f2bf(val);
    }
    {
        int c = tid, c2 = tid + 256;
        int dir0 = c >> 8, rem0 = c & 255;
        blds[c] = (dir0 ? bbv : bfv)[(rem0 & 3) * 64 + (rem0 >> 2)];
        int dir1 = c2 >> 8, rem1 = c2 & 255;
        blds[c2] = (dir1 ? bbv : bfv)[(rem1 & 3) * 64 + (rem1 >> 2)];
    }

    short8 aFr[4][2];
#pragma unroll
    for (int mt = 0; mt < 4; ++mt) {
        int vrow = v0 + mt * 16 + l16;
        if (vrow >= VP1) vrow = VP1 - 1;
        const float* er = emb + (size_t)vrow * 64;
#pragma unroll
        for (int q = 0; q < 2; ++q) {
            const float* p = er + q * 32 + quad * 8;
            float4 x0 = *(const float4*)(p);
            float4 x1 = *(const float4*)(p + 4);
            short8 v;
            v[0] = (short)f2bf(x0.x); v[1] = (short)f2bf(x0.y);
            v[2] = (short)f2bf(x0.z); v[3] = (short)f2bf(x0.w);
            v[4] = (short)f2bf(x1.x); v[5] = (short)f2bf(x1.y);
            v[6] = (short)f2bf(x1.z); v[7] = (short)f2bf(x1.w);
            aFr[mt][q] = v;
        }
    }
    __syncthreads();

    short8 bFr[8][2];
    float biasn[8];
#pragma unroll
    for (int n = 0; n < 8; ++n) {
        int c = w * 128 + n * 16 + l16;
        biasn[n] = blds[c];
#pragma unroll
        for (int q = 0; q < 2; ++q)
            bFr[n][q] = *(const short8*)&wlds[c][q * 32 + quad * 8];
    }

    float4v acc[4][8];
#pragma unroll
    for (int mt = 0; mt < 4; ++mt)
#pragma unroll
        for (int n = 0; n < 8; ++n) {
            acc[mt][n][0] = biasn[n]; acc[mt][n][1] = biasn[n];
            acc[mt][n][2] = biasn[n]; acc[mt][n][3] = biasn[n];
        }
#pragma unroll
    for (int mt = 0; mt < 4; ++mt)
#pragma unroll
        for (int n = 0; n < 8; ++n) {
            acc[mt][n] = __builtin_amdgcn_mfma_f32_16x16x32_bf16(aFr[mt][0], bFr[n][0], acc[mt][n], 0, 0, 0);
            acc[mt][n] = __builtin_amdgcn_mfma_f32_16x16x32_bf16(aFr[mt][1], bFr[n][1], acc[mt][n], 0, 0, 0);
        }

    __syncthreads();

#pragma unroll
    for (int mt = 0; mt < 4; ++mt)
#pragma unroll
        for (int n = 0; n < 8; ++n) {
            int cc = w * 128 + n * 16 + l16;
#pragma unroll
            for (int r = 0; r < 4; ++r)
                clds[mt * 16 + quad * 4 + r][cc] = f2bf(acc[mt][n][r]);
        }
    __syncthreads();

#pragma unroll
    for (int it = 0; it < 16; ++it) {
        int idx = it * 256 + tid;
        int row = idx >> 6, chunk = idx & 63;
        if (v0 + row < VP1) {
            uint4 val = *(const uint4*)&clds[row][chunk * 8];
            *(uint4*)(embw + (size_t)(v0 + row) * 512 + chunk * 8) = val;
        }
    }
}

// ---------------------------------------------------------------------------
// Recurrence (unchanged from R6): grid 256 = 2 dirs x 128 slices of 4 rows.
// ---------------------------------------------------------------------------
__global__ __launch_bounds__(256, 1)
void rec_kernel(const int* __restrict__ tokens,
                const unsigned short* __restrict__ embw,
                const float* __restrict__ Uf, const float* __restrict__ Ub,
                const float* __restrict__ Wd,
                float* __restrict__ potf, float* __restrict__ potb)
{
    const int blk = blockIdx.x;
    const int dir = blk >> 7;
    const int row0 = (blk & 127) * 4;
    const int tid = threadIdx.x;
    const int lane = tid & 63;
    const int w = tid >> 6;
    const int l16 = lane & 15, quad = lane >> 4;
    const int u = w * 16 + l16;

    const float* Up = dir ? Ub : Uf;
    float* pot = dir ? potb : potf;
    const uint2* ebase = (const uint2*)embw + dir * 64 + u;

    __shared__ int tokl[4][TT];
    __shared__ __align__(16) unsigned short hl[2][16][72];

    for (int i = tid; i < 2 * 16 * 72; i += 256)
        ((unsigned short*)hl)[i] = 0;
    for (int i = tid; i < 4 * TT; i += 256) {
        int r = i >> 9, t = i & 511;
        tokl[r][t] = tokens[(row0 + r) * TT + t];
    }

    short8 bU[4][2];
#pragma unroll
    for (int g = 0; g < 4; ++g)
#pragma unroll
        for (int q = 0; q < 2; ++q) {
            short8 v;
#pragma unroll
            for (int j = 0; j < 8; ++j) {
                int k = q * 32 + quad * 8 + j;
                v[j] = (short)f2bf(Up[k * 256 + g * 64 + u]);
            }
            bU[g][q] = v;
        }
    short8 bW[2];
#pragma unroll
    for (int q = 0; q < 2; ++q) {
        short8 v;
#pragma unroll
        for (int j = 0; j < 8; ++j) {
            int k = q * 32 + quad * 8 + j;
            v[j] = (l16 < KK) ? (short)f2bf(Wd[(dir * 64 + k) * KK + l16]) : (short)0;
        }
        bW[q] = v;
    }

    __syncthreads();

    int tokA[4], tokB[4];
    uint2 zxp[4];
#pragma unroll
    for (int d = 0; d < 4; ++d) {
        int td = dir ? (TT - 1 - d) : d;
        int td4 = dir ? (TT - 1 - (d + 4)) : (d + 4);
        tokA[d] = tokl[quad][td];
        tokB[d] = tokl[quad][td4];
    }
#pragma unroll
    for (int d = 0; d < 4; ++d)
        zxp[d] = ebase[(size_t)tokA[d] << 7];

    float c_st = 0.f, h_st = 0.f;

    float4v accg[4];
#pragma unroll
    for (int g = 0; g < 4; ++g) {
        accg[g][0] = 0.f; accg[g][1] = 0.f; accg[g][2] = 0.f; accg[g][3] = 0.f;
    }

    const int tprev0 = dir ? (w == 0 ? TT - 4 : TT - w) : (w == 0 ? 3 : w - 1);
    int vOff = (((row0 + quad) * TT + tprev0) * KK + l16) * 4;
    const int vStep = (dir ? -4 : 4) * KK * 4;

    for (int sb = 0; sb < TT; sb += 4) {
#pragma unroll
        for (int ss = 0; ss < 4; ++ss) {
            const int s = sb + ss;
            int tcur = tokA[ss];
            uint2 zcur = zxp[ss];

            hl[ss & 1][quad * 4][u] = f2bf(h_st);

            if (s + 4 < TT)
                zxp[ss] = ebase[(size_t)tokB[ss] << 7];
            tokA[ss] = tokB[ss];

            block_sync_lds();

            const unsigned short* hrow = &hl[ss & 1][l16][0];
            short8 a0 = *(const short8*)(hrow + quad * 8);
            short8 a1 = *(const short8*)(hrow + 32 + quad * 8);

            if (s + 8 < TT) {
                int t8 = dir ? (TT - 1 - (s + 8)) : (s + 8);
                tokB[ss] = tokl[quad][t8];
            }

            accg[0][0] = bflo2f(zcur.x);
            accg[1][0] = bfhi2f(zcur.x);
            accg[2][0] = bflo2f(zcur.y);
            accg[3][0] = bfhi2f(zcur.y);
#pragma unroll
            for (int g = 0; g < 4; ++g) {
                accg[g] = __builtin_amdgcn_mfma_f32_16x16x32_bf16(a0, bU[g][0], accg[g], 0, 0, 0);
                accg[g] = __builtin_amdgcn_mfma_f32_16x16x32_bf16(a1, bU[g][1], accg[g], 0, 0, 0);
            }

            if (w == ss && s > 0) {
                float4v accP = {0.f, 0.f, 0.f, 0.f};
                accP = __builtin_amdgcn_mfma_f32_16x16x32_bf16(a0, bW[0], accP, 0, 0, 0);
                accP = __builtin_amdgcn_mfma_f32_16x16x32_bf16(a1, bW[1], accP, 0, 0, 0);
                if (l16 < KK)
                    *(float*)((char*)pot + vOff) = accP[0];
                vOff += vStep;
            }

            {
                float zi = accg[0][0], zf = accg[1][0], zg = accg[2][0], zo = accg[3][0];
                float cn = sigm(zf) * c_st + sigm(zi) * tanh_(zg);
                float hn = sigm(zo) * tanh_(cn);
                bool m = (tcur != 0);
                h_st = m ? hn : h_st;
                c_st = m ? cn : c_st;
            }
        }
    }

    hl[0][quad * 4][u] = f2bf(h_st);
    block_sync_lds();
    if (w == 0) {
        const unsigned short* hrow = &hl[0][l16][0];
        short8 a0 = *(const short8*)(hrow + quad * 8);
        short8 a1 = *(const short8*)(hrow + 32 + quad * 8);
        float4v accP = {0.f, 0.f, 0.f, 0.f};
        accP = __builtin_amdgcn_mfma_f32_16x16x32_bf16(a0, bW[0], accP, 0, 0, 0);
        accP = __builtin_amdgcn_mfma_f32_16x16x32_bf16(a1, bW[1], accP, 0, 0, 0);
        int tlast = dir ? 0 : (TT - 1);
        if (l16 < KK)
            pot[((size_t)(row0 + quad) * TT + tlast) * KK + l16] = accP[0];
    }
}

// ---------------------------------------------------------------------------
// Fused combine + Viterbi. Alpha broadcast via v_readlane (SGPR, no LDS
// latency) instead of __shfl/ds_bpermute. bd folded into pl at staging.
// ---------------------------------------------------------------------------
__global__ __launch_bounds__(64)
void viterbi_kernel(const int* __restrict__ tokens,
                    const float* __restrict__ potf, const float* __restrict__ potb,
                    const float* __restrict__ bd, const float* __restrict__ trans,
                    float* __restrict__ dec_out, float* __restrict__ pot_out,
                    float* __restrict__ seq_out)
{
    const int row = blockIdx.x;
    const int lane = threadIdx.x;

    __shared__ float pl[TT * KK];
    __shared__ unsigned char bpl[(TT - 1) * KK];
    __shared__ unsigned char maskl[TT];
    __shared__ unsigned char segmap[64][KK];
    __shared__ unsigned char bseq[65];
    __shared__ float decl_[TT];
    __shared__ float bdl[16];

    if (lane < KK) bdl[lane] = bd[lane];

    int cnt = 0;
#pragma unroll
    for (int ch = 0; ch < TT / 64; ++ch) {
        int tk = tokens[row * TT + ch * 64 + lane];
        int m = (tk != 0) ? 1 : 0;
        maskl[ch * 64 + lane] = (unsigned char)m;
        cnt += m;
    }
    for (int off = 32; off > 0; off >>= 1) cnt += __shfl_down(cnt, off);
    if (lane == 0) seq_out[row] = (float)cnt;

    // stage pl = potf + potb + bd (final potentials); same value to pot_out.
    // li % 9 tracked incrementally: li = i*64+lane, 64 % 9 == 1.
    const size_t base = (size_t)row * (TT * KK);
    int r9 = lane % KK;
    for (int i = 0; i < (TT * KK) / 64; ++i) {
        int li = i * 64 + lane;
        float s = potf[base + li] + potb[base + li] + bdl[r9];
        pl[li] = s;
        pot_out[base + li] = s;
        r9 = (r9 + 1 == KK) ? 0 : r9 + 1;
    }
    __syncthreads();

    float treg[KK];
#pragma unroll
    for (int i = 0; i < KK; ++i) treg[i] = (lane < KK) ? trans[i * KK + lane] : 0.f;

    float alpha = (lane < KK) ? pl[lane] : -1e30f;
    float pnext = (lane < KK) ? pl[KK + lane] : 0.f;
    int mnext = maskl[1];
    for (int t = 1; t < TT; ++t) {
        float p = pnext;
        int m = mnext;
        if (t + 1 < TT) {
            pnext = (lane < KK) ? pl[(t + 1) * KK + lane] : 0.f;
            mnext = maskl[t + 1];
        }
        float sc[KK];
#pragma unroll
        for (int i = 0; i < KK; ++i) sc[i] = bcast(alpha, i) + treg[i];
        // tree argmax, first-max tie rule
        float b0 = sc[0]; int i0 = 0;
        if (sc[1] > b0) { b0 = sc[1]; i0 = 1; }
        float b1 = sc[2]; int i1 = 2;
        if (sc[3] > b1) { b1 = sc[3]; i1 = 3; }
        float b2 = sc[4]; int i2 = 4;
        if (sc[5] > b2) { b2 = sc[5]; i2 = 5; }
        float b3 = sc[6]; int i3 = 6;
        if (sc[7] > b3) { b3 = sc[7]; i3 = 7; }
        if (b1 > b0) { b0 = b1; i0 = i1; }
        if (b3 > b2) { b2 = b3; i2 = i3; }
        if (b2 > b0) { b0 = b2; i0 = i2; }
        if (sc[8] > b0) { b0 = sc[8]; i0 = 8; }

        alpha = m ? (b0 + p) : alpha;
        int bpv = m ? i0 : lane;
        if (lane < KK) bpl[(t - 1) * KK + lane] = (unsigned char)bpv;
    }
    float sc[KK];
#pragma unroll
    for (int i = 0; i < KK; ++i) sc[i] = bcast(alpha, i);
    float b0 = sc[0]; int last = 0;
#pragma unroll
    for (int i = 1; i < KK; ++i)
        if (sc[i] > b0) { b0 = sc[i]; last = i; }
    __syncthreads();

    {
        int l = lane;
#pragma unroll
        for (int x = 0; x < KK; ++x) {
            int y = x;
#pragma unroll
            for (int d = 7; d >= 0; --d) {
                int t = 8 * l + d;
                if (t < TT - 1) y = bpl[t * KK + y];
            }
            segmap[l][x] = (unsigned char)y;
        }
    }
    __syncthreads();
    if (lane == 0) {
        int cur = last;
        bseq[64] = (unsigned char)last;
        for (int l = 63; l >= 0; --l) {
            cur = segmap[l][cur];
            bseq[l] = (unsigned char)cur;
        }
    }
    __syncthreads();
    {
        int l = lane;
        int cur = bseq[l + 1];
#pragma unroll
        for (int d = 7; d >= 0; --d) {
            int t = 8 * l + d;
            if (t < TT - 1) cur = bpl[t * KK + cur];
            decl_[t] = (maskl[t] != 0) ? (float)cur : 0.f;
        }
    }
    __syncthreads();
#pragma unroll
    for (int ch = 0; ch < TT / 64; ++ch)
        dec_out[(size_t)row * TT + ch * 64 + lane] = decl_[ch * 64 + lane];
}

extern "C" void kernel_launch(void* const* d_in, const int* in_sizes, int n_in,
                              void* d_out, int out_size, void* d_ws, size_t ws_size,
                              hipStream_t stream)
{
    const int*   tokens = (const int*)d_in[0];
    const float* emb    = (const float*)d_in[1];
    const float* Wf     = (const float*)d_in[2];
    const float* Uf     = (const float*)d_in[3];
    const float* bfv    = (const float*)d_in[4];
    const float* Wb     = (const float*)d_in[5];
    const float* Ub     = (const float*)d_in[6];
    const float* bbv    = (const float*)d_in[7];
    const float* Wd     = (const float*)d_in[8];
    const float* bd     = (const float*)d_in[9];
    const float* trans  = (const float*)d_in[10];

    float* out     = (float*)d_out;
    float* dec_out = out;
    float* pot_out = out + (size_t)BB * TT;
    float* seq_out = out + (size_t)BB * TT + BTK;

    float* potf = (float*)d_ws;
    float* potb = potf + BTK;
    unsigned short* embw = (unsigned short*)(potb + BTK);

    hipLaunchKernelGGL(embw_kernel, dim3(469), dim3(256), 0, stream,
                       emb, Wf, bfv, Wb, bbv, embw);
    hipLaunchKernelGGL(rec_kernel, dim3(256), dim3(256), 0, stream,
                       tokens, embw, Uf, Ub, Wd, potf, potb);
    hipLaunchKernelGGL(viterbi_kernel, dim3(BB), dim3(64), 0, stream,
                       tokens, potf, potb, bd, trans, dec_out, pot_out, seq_out);
}

// Round 8
// 398.072 us; speedup vs baseline: 1.3122x; 1.0034x over previous
//
#include <hip/hip_runtime.h>

#define BB 512
#define TT 512
#define KK 9
#define VP1 30001   // V+1 rows in emb
#define BTK ((size_t)BB * TT * KK)

typedef __attribute__((ext_vector_type(8))) short short8;
typedef __attribute__((ext_vector_type(4))) float float4v;

__device__ __forceinline__ float sigm(float x) {
    return __builtin_amdgcn_rcpf(1.0f + __expf(-x));
}
__device__ __forceinline__ float tanh_(float x) {
    return 1.0f - 2.0f * __builtin_amdgcn_rcpf(__expf(2.0f * x) + 1.0f);
}

__device__ __forceinline__ unsigned short f2bf(float f) {
    unsigned int u = __float_as_uint(f);
    unsigned int r = u + 0x7fffu + ((u >> 16) & 1u);
    return (unsigned short)(r >> 16);
}
__device__ __forceinline__ float bflo2f(unsigned int d) { return __uint_as_float(d << 16); }
__device__ __forceinline__ float bfhi2f(unsigned int d) { return __uint_as_float(d & 0xffff0000u); }

// broadcast lane i's float via SGPR
__device__ __forceinline__ float bcast(float v, int i) {
    return __uint_as_float(__builtin_amdgcn_readlane(__float_as_uint(v), i));
}

// barrier that does NOT drain vmcnt. 0xC07F = vmcnt(63) expcnt(7) lgkmcnt(0).
__device__ __forceinline__ void block_sync_lds() {
    __builtin_amdgcn_s_waitcnt(0xC07F);
    __builtin_amdgcn_s_barrier();
}

// ---------------------------------------------------------------------------
// One-time W swizzle: wswz[c][k] = bf16(W_dir[k][g*64+u]), c = dir*256+u*4+g;
// bsw[c] = bias. Runs once (8 blocks); output aliased onto potf workspace
// (rec writes potf only after embw has consumed wswz).
// ---------------------------------------------------------------------------
__global__ __launch_bounds__(256)
void wswz_kernel(const float* __restrict__ Wf, const float* __restrict__ bfv,
                 const float* __restrict__ Wb, const float* __restrict__ bbv,
                 unsigned short* __restrict__ wswz, float* __restrict__ bsw)
{
    const int tid = threadIdx.x;
#pragma unroll
    for (int it = 0; it < 16; ++it) {
        int o = blockIdx.x * 4096 + it * 256 + tid;   // o = c*64 + k
        int k = o & 63, c = o >> 6;
        int dir = c >> 8, rem = c & 255;
        int u = rem >> 2, g = rem & 3;
        float val = (dir ? Wb : Wf)[k * 256 + g * 64 + u];
        wswz[o] = f2bf(val);
    }
    if (blockIdx.x == 0) {
#pragma unroll
        for (int h = 0; h < 2; ++h) {
            int c = h * 256 + tid;
            int dir = c >> 8, rem = c & 255;
            bsw[c] = (dir ? bbv : bfv)[(rem & 3) * 64 + (rem >> 2)];
        }
    }
}

// ---------------------------------------------------------------------------
// embW[v][c] (bf16) = emb[v,:] @ Wswz[:,c] + bsw[c]. B-frags straight from the
// 64 KB L2-hot wswz table (no per-block staging).
// ---------------------------------------------------------------------------
__global__ __launch_bounds__(256, 1)
void embw_kernel(const float* __restrict__ emb,
                 const unsigned short* __restrict__ wswz, const float* __restrict__ bsw,
                 unsigned short* __restrict__ embw)
{
    const int v0 = blockIdx.x * 64;
    const int tid = threadIdx.x;
    const int w = tid >> 6, lane = tid & 63;
    const int l16 = lane & 15, quad = lane >> 4;

    __shared__ __align__(16) unsigned short clds[64][520];

    // B fragments + bias from global (hot)
    short8 bFr[8][2];
    float biasn[8];
#pragma unroll
    for (int n = 0; n < 8; ++n) {
        int c = w * 128 + n * 16 + l16;
        biasn[n] = bsw[c];
        const unsigned short* wp = wswz + c * 64;
#pragma unroll
        for (int q = 0; q < 2; ++q)
            bFr[n][q] = *(const short8*)(wp + q * 32 + quad * 8);
    }

    // A fragments (emb rows, f32 -> bf16)
    short8 aFr[4][2];
#pragma unroll
    for (int mt = 0; mt < 4; ++mt) {
        int vrow = v0 + mt * 16 + l16;
        if (vrow >= VP1) vrow = VP1 - 1;
        const float* er = emb + (size_t)vrow * 64;
#pragma unroll
        for (int q = 0; q < 2; ++q) {
            const float* p = er + q * 32 + quad * 8;
            float4 x0 = *(const float4*)(p);
            float4 x1 = *(const float4*)(p + 4);
            short8 v;
            v[0] = (short)f2bf(x0.x); v[1] = (short)f2bf(x0.y);
            v[2] = (short)f2bf(x0.z); v[3] = (short)f2bf(x0.w);
            v[4] = (short)f2bf(x1.x); v[5] = (short)f2bf(x1.y);
            v[6] = (short)f2bf(x1.z); v[7] = (short)f2bf(x1.w);
            aFr[mt][q] = v;
        }
    }

    float4v acc[4][8];
#pragma unroll
    for (int mt = 0; mt < 4; ++mt)
#pragma unroll
        for (int n = 0; n < 8; ++n) {
            acc[mt][n][0] = biasn[n]; acc[mt][n][1] = biasn[n];
            acc[mt][n][2] = biasn[n]; acc[mt][n][3] = biasn[n];
        }
#pragma unroll
    for (int mt = 0; mt < 4; ++mt)
#pragma unroll
        for (int n = 0; n < 8; ++n) {
            acc[mt][n] = __builtin_amdgcn_mfma_f32_16x16x32_bf16(aFr[mt][0], bFr[n][0], acc[mt][n], 0, 0, 0);
            acc[mt][n] = __builtin_amdgcn_mfma_f32_16x16x32_bf16(aFr[mt][1], bFr[n][1], acc[mt][n], 0, 0, 0);
        }

    // C -> LDS repack, then coalesced stores
#pragma unroll
    for (int mt = 0; mt < 4; ++mt)
#pragma unroll
        for (int n = 0; n < 8; ++n) {
            int cc = w * 128 + n * 16 + l16;
#pragma unroll
            for (int r = 0; r < 4; ++r)
                clds[mt * 16 + quad * 4 + r][cc] = f2bf(acc[mt][n][r]);
        }
    __syncthreads();

#pragma unroll
    for (int it = 0; it < 16; ++it) {
        int idx = it * 256 + tid;
        int row = idx >> 6, chunk = idx & 63;
        if (v0 + row < VP1) {
            uint4 val = *(const uint4*)&clds[row][chunk * 8];
            *(uint4*)(embw + (size_t)(v0 + row) * 512 + chunk * 8) = val;
        }
    }
}

// ---------------------------------------------------------------------------
// Recurrence (unchanged from R6/R7 — control): grid 256 = 2 dirs x 128 slices.
// ---------------------------------------------------------------------------
__global__ __launch_bounds__(256, 1)
void rec_kernel(const int* __restrict__ tokens,
                const unsigned short* __restrict__ embw,
                const float* __restrict__ Uf, const float* __restrict__ Ub,
                const float* __restrict__ Wd,
                float* __restrict__ potf, float* __restrict__ potb)
{
    const int blk = blockIdx.x;
    const int dir = blk >> 7;
    const int row0 = (blk & 127) * 4;
    const int tid = threadIdx.x;
    const int lane = tid & 63;
    const int w = tid >> 6;
    const int l16 = lane & 15, quad = lane >> 4;
    const int u = w * 16 + l16;

    const float* Up = dir ? Ub : Uf;
    float* pot = dir ? potb : potf;
    const uint2* ebase = (const uint2*)embw + dir * 64 + u;

    __shared__ int tokl[4][TT];
    __shared__ __align__(16) unsigned short hl[2][16][72];

    for (int i = tid; i < 2 * 16 * 72; i += 256)
        ((unsigned short*)hl)[i] = 0;
    for (int i = tid; i < 4 * TT; i += 256) {
        int r = i >> 9, t = i & 511;
        tokl[r][t] = tokens[(row0 + r) * TT + t];
    }

    short8 bU[4][2];
#pragma unroll
    for (int g = 0; g < 4; ++g)
#pragma unroll
        for (int q = 0; q < 2; ++q) {
            short8 v;
#pragma unroll
            for (int j = 0; j < 8; ++j) {
                int k = q * 32 + quad * 8 + j;
                v[j] = (short)f2bf(Up[k * 256 + g * 64 + u]);
            }
            bU[g][q] = v;
        }
    short8 bW[2];
#pragma unroll
    for (int q = 0; q < 2; ++q) {
        short8 v;
#pragma unroll
        for (int j = 0; j < 8; ++j) {
            int k = q * 32 + quad * 8 + j;
            v[j] = (l16 < KK) ? (short)f2bf(Wd[(dir * 64 + k) * KK + l16]) : (short)0;
        }
        bW[q] = v;
    }

    __syncthreads();

    int tokA[4], tokB[4];
    uint2 zxp[4];
#pragma unroll
    for (int d = 0; d < 4; ++d) {
        int td = dir ? (TT - 1 - d) : d;
        int td4 = dir ? (TT - 1 - (d + 4)) : (d + 4);
        tokA[d] = tokl[quad][td];
        tokB[d] = tokl[quad][td4];
    }
#pragma unroll
    for (int d = 0; d < 4; ++d)
        zxp[d] = ebase[(size_t)tokA[d] << 7];

    float c_st = 0.f, h_st = 0.f;

    float4v accg[4];
#pragma unroll
    for (int g = 0; g < 4; ++g) {
        accg[g][0] = 0.f; accg[g][1] = 0.f; accg[g][2] = 0.f; accg[g][3] = 0.f;
    }

    const int tprev0 = dir ? (w == 0 ? TT - 4 : TT - w) : (w == 0 ? 3 : w - 1);
    int vOff = (((row0 + quad) * TT + tprev0) * KK + l16) * 4;
    const int vStep = (dir ? -4 : 4) * KK * 4;

    for (int sb = 0; sb < TT; sb += 4) {
#pragma unroll
        for (int ss = 0; ss < 4; ++ss) {
            const int s = sb + ss;
            int tcur = tokA[ss];
            uint2 zcur = zxp[ss];

            hl[ss & 1][quad * 4][u] = f2bf(h_st);

            if (s + 4 < TT)
                zxp[ss] = ebase[(size_t)tokB[ss] << 7];
            tokA[ss] = tokB[ss];

            block_sync_lds();

            const unsigned short* hrow = &hl[ss & 1][l16][0];
            short8 a0 = *(const short8*)(hrow + quad * 8);
            short8 a1 = *(const short8*)(hrow + 32 + quad * 8);

            if (s + 8 < TT) {
                int t8 = dir ? (TT - 1 - (s + 8)) : (s + 8);
                tokB[ss] = tokl[quad][t8];
            }

            accg[0][0] = bflo2f(zcur.x);
            accg[1][0] = bfhi2f(zcur.x);
            accg[2][0] = bflo2f(zcur.y);
            accg[3][0] = bfhi2f(zcur.y);
#pragma unroll
            for (int g = 0; g < 4; ++g) {
                accg[g] = __builtin_amdgcn_mfma_f32_16x16x32_bf16(a0, bU[g][0], accg[g], 0, 0, 0);
                accg[g] = __builtin_amdgcn_mfma_f32_16x16x32_bf16(a1, bU[g][1], accg[g], 0, 0, 0);
            }

            if (w == ss && s > 0) {
                float4v accP = {0.f, 0.f, 0.f, 0.f};
                accP = __builtin_amdgcn_mfma_f32_16x16x32_bf16(a0, bW[0], accP, 0, 0, 0);
                accP = __builtin_amdgcn_mfma_f32_16x16x32_bf16(a1, bW[1], accP, 0, 0, 0);
                if (l16 < KK)
                    *(float*)((char*)pot + vOff) = accP[0];
                vOff += vStep;
            }

            {
                float zi = accg[0][0], zf = accg[1][0], zg = accg[2][0], zo = accg[3][0];
                float cn = sigm(zf) * c_st + sigm(zi) * tanh_(zg);
                float hn = sigm(zo) * tanh_(cn);
                bool m = (tcur != 0);
                h_st = m ? hn : h_st;
                c_st = m ? cn : c_st;
            }
        }
    }

    hl[0][quad * 4][u] = f2bf(h_st);
    block_sync_lds();
    if (w == 0) {
        const unsigned short* hrow = &hl[0][l16][0];
        short8 a0 = *(const short8*)(hrow + quad * 8);
        short8 a1 = *(const short8*)(hrow + 32 + quad * 8);
        float4v accP = {0.f, 0.f, 0.f, 0.f};
        accP = __builtin_amdgcn_mfma_f32_16x16x32_bf16(a0, bW[0], accP, 0, 0, 0);
        accP = __builtin_amdgcn_mfma_f32_16x16x32_bf16(a1, bW[1], accP, 0, 0, 0);
        int tlast = dir ? 0 : (TT - 1);
        if (l16 < KK)
            pot[((size_t)(row0 + quad) * TT + tlast) * KK + l16] = accP[0];
    }
}

// ---------------------------------------------------------------------------
// Fused combine + Viterbi. readlane broadcast + max3 value-max + equality
// cascade for first-max index; padded LDS kills the t+1 guard; unroll 4.
// ---------------------------------------------------------------------------
__global__ __launch_bounds__(64)
void viterbi_kernel(const int* __restrict__ tokens,
                    const float* __restrict__ potf, const float* __restrict__ potb,
                    const float* __restrict__ bd, const float* __restrict__ trans,
                    float* __restrict__ dec_out, float* __restrict__ pot_out,
                    float* __restrict__ seq_out)
{
    const int row = blockIdx.x;
    const int lane = threadIdx.x;

    __shared__ float pl[TT * KK + 16];      // padded: t+1 == TT read is safe
    __shared__ unsigned char bpl[(TT - 1) * KK];
    __shared__ unsigned char maskl[TT + 8]; // padded
    __shared__ unsigned char segmap[64][KK];
    __shared__ unsigned char bseq[65];
    __shared__ float decl_[TT];
    __shared__ float bdl[16];

    if (lane < KK) bdl[lane] = bd[lane];
    if (lane < 8) maskl[TT + lane] = 0;
    pl[TT * KK + lane % 16] = 0.f;

    int cnt = 0;
#pragma unroll
    for (int ch = 0; ch < TT / 64; ++ch) {
        int tk = tokens[row * TT + ch * 64 + lane];
        int m = (tk != 0) ? 1 : 0;
        maskl[ch * 64 + lane] = (unsigned char)m;
        cnt += m;
    }
    for (int off = 32; off > 0; off >>= 1) cnt += __shfl_down(cnt, off);
    if (lane == 0) seq_out[row] = (float)cnt;

    const size_t base = (size_t)row * (TT * KK);
    int r9 = lane % KK;
    for (int i = 0; i < (TT * KK) / 64; ++i) {
        int li = i * 64 + lane;
        float s = potf[base + li] + potb[base + li] + bdl[r9];
        pl[li] = s;
        pot_out[base + li] = s;
        r9 = (r9 + 1 == KK) ? 0 : r9 + 1;
    }
    __syncthreads();

    float treg[KK];
#pragma unroll
    for (int i = 0; i < KK; ++i) treg[i] = (lane < KK) ? trans[i * KK + lane] : 0.f;

    float alpha = (lane < KK) ? pl[lane] : -1e30f;
    float pnext = (lane < KK) ? pl[KK + lane] : 0.f;
    int mnext = maskl[1];
#pragma unroll 4
    for (int t = 1; t < TT; ++t) {
        float p = pnext;
        int m = mnext;
        pnext = (lane < KK) ? pl[(t + 1) * KK + lane] : 0.f;  // pad makes t+1==TT safe
        mnext = maskl[t + 1];

        float sc[KK];
#pragma unroll
        for (int i = 0; i < KK; ++i) sc[i] = bcast(alpha, i) + treg[i];
        // value max via max3 folds (depth 2)
        float b0 = fmaxf(fmaxf(fmaxf(sc[0], sc[1]), sc[2]),
                   fmaxf(fmaxf(fmaxf(sc[3], sc[4]), sc[5]),
                         fmaxf(fmaxf(sc[6], sc[7]), sc[8])));
        // first-max index: cascade from high to low
        int i0 = 8;
#pragma unroll
        for (int i = 7; i >= 0; --i) i0 = (sc[i] == b0) ? i : i0;

        alpha = m ? (b0 + p) : alpha;
        int bpv = m ? i0 : lane;
        if (lane < KK) bpl[(t - 1) * KK + lane] = (unsigned char)bpv;
    }
    float sc[KK];
#pragma unroll
    for (int i = 0; i < KK; ++i) sc[i] = bcast(alpha, i);
    float b0 = fmaxf(fmaxf(fmaxf(sc[0], sc[1]), sc[2]),
               fmaxf(fmaxf(fmaxf(sc[3], sc[4]), sc[5]),
                     fmaxf(fmaxf(sc[6], sc[7]), sc[8])));
    int last = 8;
#pragma unroll
    for (int i = 7; i >= 0; --i) last = (sc[i] == b0) ? i : last;
    __syncthreads();

    {
        int l = lane;
#pragma unroll
        for (int x = 0; x < KK; ++x) {
            int y = x;
#pragma unroll
            for (int d = 7; d >= 0; --d) {
                int t = 8 * l + d;
                if (t < TT - 1) y = bpl[t * KK + y];
            }
            segmap[l][x] = (unsigned char)y;
        }
    }
    __syncthreads();
    if (lane == 0) {
        int cur = last;
        bseq[64] = (unsigned char)last;
        for (int l = 63; l >= 0; --l) {
            cur = segmap[l][cur];
            bseq[l] = (unsigned char)cur;
        }
    }
    __syncthreads();
    {
        int l = lane;
        int cur = bseq[l + 1];
#pragma unroll
        for (int d = 7; d >= 0; --d) {
            int t = 8 * l + d;
            if (t < TT - 1) cur = bpl[t * KK + cur];
            decl_[t] = (maskl[t] != 0) ? (float)cur : 0.f;
        }
    }
    __syncthreads();
#pragma unroll
    for (int ch = 0; ch < TT / 64; ++ch)
        dec_out[(size_t)row * TT + ch * 64 + lane] = decl_[ch * 64 + lane];
}

extern "C" void kernel_launch(void* const* d_in, const int* in_sizes, int n_in,
                              void* d_out, int out_size, void* d_ws, size_t ws_size,
                              hipStream_t stream)
{
    const int*   tokens = (const int*)d_in[0];
    const float* emb    = (const float*)d_in[1];
    const float* Wf     = (const float*)d_in[2];
    const float* Uf     = (const float*)d_in[3];
    const float* bfv    = (const float*)d_in[4];
    const float* Wb     = (const float*)d_in[5];
    const float* Ub     = (const float*)d_in[6];
    const float* bbv    = (const float*)d_in[7];
    const float* Wd     = (const float*)d_in[8];
    const float* bd     = (const float*)d_in[9];
    const float* trans  = (const float*)d_in[10];

    float* out     = (float*)d_out;
    float* dec_out = out;
    float* pot_out = out + (size_t)BB * TT;
    float* seq_out = out + (size_t)BB * TT + BTK;

    float* potf = (float*)d_ws;
    float* potb = potf + BTK;
    unsigned short* embw = (unsigned short*)(potb + BTK);
    // wswz/bsw alias the potf region: consumed by embw_kernel BEFORE rec_kernel
    // writes potf (stream-ordered), so no extra workspace needed.
    unsigned short* wswz = (unsigned short*)potf;
    float* bsw = (float*)((char*)potf + 512 * 64 * sizeof(unsigned short));

    hipLaunchKernelGGL(wswz_kernel, dim3(8), dim3(256), 0, stream,
                       Wf, bfv, Wb, bbv, wswz, bsw);
    hipLaunchKernelGGL(embw_kernel, dim3(469), dim3(256), 0, stream,
                       emb, wswz, bsw, embw);
    hipLaunchKernelGGL(rec_kernel, dim3(256), dim3(256), 0, stream,
                       tokens, embw, Uf, Ub, Wd, potf, potb);
    hipLaunchKernelGGL(viterbi_kernel, dim3(BB), dim3(64), 0, stream,
                       tokens, potf, potb, bd, trans, dec_out, pot_out, seq_out);
}